// Round 7
// baseline (136.902 us; speedup 1.0000x reference)
//
#include <hip/hip_runtime.h>
#include <hip/hip_bf16.h>
#include <cstddef>
#include <cstdint>

// Direct-conv reformulation of the Winograd reference (validated r1-r6):
// out[b,o,2i+p,2j+q] = bias[o] + sum_{c,y,x} xpad[b,c,2i-1+y,2j-1+x] * Keff[o,c,p,q,y,x]
// Implicit GEMM: M=65536 patches, N=384 (o*4+p*2+q), K=1024 (c*16+y*4+x), bf16 MFMA.
// Round 7: bf16-in-LDS with +1 column shift (pads stored as zeros) so a B-frag is
// 4 dwords = 2x ds_read2_b32, no cvt/mask in the MFMA loop. Reg-staged (T14)
// one chunk ahead; one barrier + lgkmcnt(0) per chunk (no vmcnt(0) drain).
// Bank-free layout: row pitch 165 dw (odd, 2P=10 mod 32), c_sub col offset 80 dw
// (=16 mod 32) -> every read/write instr uniform 2-way (free). N=128/block.

#define IHW 128
#define CIN 64
#define COUT 96
#define NCK 16
#define P_DW 165
#define COFF_DW 80
#define BUF_DW (12 * P_DW)  // 1980 dwords per buffer (12 rows x 2 channels each)

typedef __attribute__((ext_vector_type(8))) short short8_t;  // bf16x8 operand
typedef __attribute__((ext_vector_type(4))) float floatx4;   // f32 accum

__device__ __forceinline__ short bf16r(float f) {  // RNE fp32->bf16 (keff precompute)
  uint32_t u = __float_as_uint(f);
  uint32_t r = (u + 0x7FFFu + ((u >> 16) & 1u)) >> 16;
  return (short)r;
}

__device__ __forceinline__ uint32_t pk(float lo, float hi) {  // bf16 pair pack (hw cvt)
  union { __hip_bfloat16 h; unsigned short s; } a, bq;
  a.h = __float2bfloat16(lo);
  bq.h = __float2bfloat16(hi);
  return (uint32_t)a.s | ((uint32_t)bq.s << 16);
}

// ---------------- Keff precompute ----------------
__global__ void keff_kernel(const float* __restrict__ w, short* __restrict__ keff) {
  int idx = blockIdx.x * 256 + threadIdx.x;
  if (idx >= COUT * CIN) return;
  int o = idx / CIN, c = idx % CIN;
  int g = o / 32;

  int perm[4] = {0, 1, 2, 3};
  if (g == 1) { perm[0] = 1; perm[1] = 0; }
  else if (g == 2) { perm[0] = 3; perm[3] = 0; }

  const float H[4][4] = {{1,1,1,1},{1,-1,1,-1},{1,1,-1,-1},{1,-1,-1,1}};
  float S[2][4];
#pragma unroll
  for (int p = 0; p < 2; ++p)
#pragma unroll
    for (int a = 0; a < 4; ++a) {
      bool pos = (g == 1) ? ((p == 0) ? true : (a < 2))
                          : ((p == 0) ? ((a & 1) == 0) : (a < 2));
      S[p][a] = pos ? 1.f : -1.f;
    }

  float wv[4][4];
#pragma unroll
  for (int a = 0; a < 4; ++a)
#pragma unroll
    for (int d = 0; d < 4; ++d) wv[a][d] = w[(o * CIN + c) * 16 + a * 4 + d];

  for (int p = 0; p < 2; ++p)
    for (int q = 0; q < 2; ++q) {
      int n = o * 4 + p * 2 + q;
      for (int y = 0; y < 4; ++y)
        for (int xx = 0; xx < 4; ++xx) {
          float s = 0.f;
#pragma unroll
          for (int a = 0; a < 4; ++a) {
            float ea = S[p][a] * H[a][perm[xx]];
#pragma unroll
            for (int d = 0; d < 4; ++d) s += ea * S[q][d] * H[d][perm[y]] * wv[a][d];
          }
          keff[n * 1024 + c * 16 + y * 4 + xx] = bf16r(s);
        }
    }
}

// ---------------- main conv kernel ----------------
// block: 256 threads = 4 waves (2 M x 2 N). Block tile M=128 patches, N=128.
// grid: 1536 = 512 tiles x 3 n-blocks, XCD-paired.
__global__ __launch_bounds__(256) void conv_mfma(const float* __restrict__ x,
                                                 const short* __restrict__ keff,
                                                 const float* __restrict__ bias,
                                                 float* __restrict__ out) {
  __shared__ uint32_t lds[2 * BUF_DW];  // 15,840 B

  const int tid = threadIdx.x;
  const int lane = tid & 63;
  const int wid = tid >> 6;
  const int wavem = wid >> 1;
  const int wn = wid & 1;
  const int l15 = lane & 15;
  const int l4 = lane >> 4;

  // XCD-aware: all 3 n-blocks of a tile + 64 consecutive tiles per XCD.
  const int hw = blockIdx.x;          // 0..1535
  const int xcd = hw & 7;
  const int r = hw >> 3;              // 0..191
  const int tile = xcd * 64 + r / 3;  // 0..511
  const int nblk = r % 3;             // 0..2
  const int b = tile >> 5;
  const int ib = tile & 31;
  const int gy0 = ib * 4 - 1;

  const float* xb = x + (size_t)b * CIN * IHW * IHW;

  // staging slots: 3 per thread; seg = c_sub*12 + (kk*6 + y); 32 lanes per segment
  int sl_off[3], sl_dw[3], sl_s[3];
  bool sl_ok[3];
#pragma unroll
  for (int it = 0; it < 3; ++it) {
    const int slot = tid + it * 256;
    const int seg = slot >> 5;
    const int s = slot & 31;
    const int c_sub = seg / 12;
    const int rr = seg % 12;  // rr = kk*6 + y
    const int kk2 = rr / 6;
    const int y = rr % 6;
    const int c_loc = 2 * kk2 + c_sub;
    const int gy = gy0 + y;
    const bool ok = (unsigned)gy < (unsigned)IHW;
    sl_off[it] = (c_loc * IHW + (ok ? gy : 0)) * IHW + 4 * s;
    sl_dw[it] = rr * P_DW + c_sub * COFF_DW;
    sl_s[it] = s;
    sl_ok[it] = ok;
  }

  float4 gv[3];
  float gn[3];
// issue chunk ckv's global loads into regs (coalesced float4 + overlap scalar)
#define ISSUE(ckv)                                                       \
  {                                                                      \
    _Pragma("unroll") for (int it = 0; it < 3; ++it) {                   \
      const float* p = xb + sl_off[it] + (size_t)(ckv) * (4 * IHW * IHW);\
      gv[it] = *reinterpret_cast<const float4*>(p);                      \
      gn[it] = (sl_s[it] < 31) ? p[4] : 0.f;                             \
    }                                                                    \
  }

// cvt + write staged regs into buffer bs (sx = gx+1 shift; pads written as zeros)
#define WRITEST(bs)                                                      \
  {                                                                      \
    uint32_t* Bp = lds + (bs) * BUF_DW;                                  \
    _Pragma("unroll") for (int it = 0; it < 3; ++it) {                   \
      float4 v = gv[it];                                                 \
      float nx = gn[it];                                                 \
      if (!sl_ok[it]) { v.x = 0.f; v.y = 0.f; v.z = 0.f; v.w = 0.f; nx = 0.f; } \
      const int o = sl_dw[it] + 2 * sl_s[it] + 1;                        \
      Bp[o] = pk(v.y, v.z);                                              \
      Bp[o + 1] = pk(v.w, nx);                                           \
      if (sl_s[it] == 0) Bp[sl_dw[it]] = pk(0.f, v.x);                   \
    }                                                                    \
  }

  floatx4 acc[4][4];
#pragma unroll
  for (int i = 0; i < 4; ++i)
#pragma unroll
    for (int j2 = 0; j2 < 4; ++j2) acc[i][j2] = (floatx4){0.f, 0.f, 0.f, 0.f};

  // A (Keff): n = nblk*128 + wn*64 + nf*16 + l15, k-slice = l4*8
  const short* kbase = keff + ((size_t)(nblk * 128 + wn * 64 + l15)) * 1024 + l4 * 8;

  float biasr[4];
#pragma unroll
  for (int nf = 0; nf < 4; ++nf) biasr[nf] = bias[nblk * 32 + wn * 16 + nf * 4 + l4];

  // per-lane compute read base (dwords): rows y0,y0+1 of c_sub half-row
  const int cm_dw = (2 * wavem + 2 * (l4 & 1)) * P_DW + (l4 >> 1) * COFF_DW + l15;

  // prologue: stage chunk 0, issue chunk 1, prime A-frags
  ISSUE(0);
  WRITEST(0);
  ISSUE(1);
  asm volatile("s_waitcnt lgkmcnt(0)" ::: "memory");
  __builtin_amdgcn_s_barrier();
  __builtin_amdgcn_sched_barrier(0);

  short8_t afc[4], afn[4];
#pragma unroll
  for (int nf = 0; nf < 4; ++nf)
    afc[nf] = *reinterpret_cast<const short8_t*>(kbase + nf * 16 * 1024);

  for (int ck = 0; ck < NCK; ++ck) {
    const uint32_t* Bp = lds + (ck & 1) * BUF_DW;
#pragma unroll
    for (int kk = 0; kk < 2; ++kk) {
      const int step = ck * 2 + kk;
      const int nstep = (step + 1) & 31;
#pragma unroll
      for (int nf = 0; nf < 4; ++nf)
        afn[nf] = *reinterpret_cast<const short8_t*>(kbase + nf * 16 * 1024 + nstep * 32);

      const int od = cm_dw + kk * (6 * P_DW);
#pragma unroll
      for (int mf = 0; mf < 4; ++mf) {
        const int o = od + mf * 16;
        union { short8_t s8; uint32_t u[4]; } frag;
        frag.u[0] = Bp[o];
        frag.u[1] = Bp[o + 1];
        frag.u[2] = Bp[o + P_DW];
        frag.u[3] = Bp[o + P_DW + 1];
#pragma unroll
        for (int nf = 0; nf < 4; ++nf)
          acc[mf][nf] = __builtin_amdgcn_mfma_f32_16x16x32_bf16(afc[nf], frag.s8,
                                                                acc[mf][nf], 0, 0, 0);
      }
#pragma unroll
      for (int nf = 0; nf < 4; ++nf) afc[nf] = afn[nf];
    }

    if (ck < NCK - 1) {
      WRITEST((ck + 1) & 1);          // stage chunk ck+1 (regs loaded last iter)
      if (ck + 2 < NCK) ISSUE(ck + 2);
      asm volatile("s_waitcnt lgkmcnt(0)" ::: "memory");
      __builtin_amdgcn_s_barrier();
      __builtin_amdgcn_sched_barrier(0);
    }
  }

  // epilogue (validated r2 mapping): o = nblk*32 + wn*16 + nf*4 + l4, pq = reg idx
  const int i_row = ib * 2 + wavem;
  const int orow0 = 2 * i_row;
#pragma unroll
  for (int nf = 0; nf < 4; ++nf) {
    const int o = nblk * 32 + wn * 16 + nf * 4 + l4;
    const float bv = biasr[nf];
    float* obase = out + ((size_t)(b * COUT + o) * IHW + orow0) * IHW;
#pragma unroll
    for (int mf = 0; mf < 4; ++mf) {
      const int col = 2 * (mf * 16 + l15);
      float2 s0 = make_float2(acc[mf][nf][0] + bv, acc[mf][nf][1] + bv);
      float2 s1 = make_float2(acc[mf][nf][2] + bv, acc[mf][nf][3] + bv);
      *reinterpret_cast<float2*>(obase + col) = s0;
      *reinterpret_cast<float2*>(obase + IHW + col) = s1;
    }
  }
#undef ISSUE
#undef WRITEST
}

extern "C" void kernel_launch(void* const* d_in, const int* in_sizes, int n_in,
                              void* d_out, int out_size, void* d_ws, size_t ws_size,
                              hipStream_t stream) {
  const float* x = (const float*)d_in[0];
  const float* w = (const float*)d_in[1];
  const float* bias = (const float*)d_in[2];
  float* out = (float*)d_out;
  short* keff = (short*)d_ws;  // 786432 B

  hipLaunchKernelGGL(keff_kernel, dim3(24), dim3(256), 0, stream, w, keff);
  hipLaunchKernelGGL(conv_mfma, dim3(1536), dim3(256), 0, stream, x, keff, bias, out);
}

// Round 8
// 78.979 us; speedup vs baseline: 1.7334x; 1.7334x over previous
//
#include <hip/hip_runtime.h>
#include <hip/hip_bf16.h>
#include <cstddef>
#include <cstdint>

// Direct-conv reformulation of the Winograd reference (validated r1-r7):
// out[b,o,2i+p,2j+q] = bias[o] + sum_{c,y,x} xpad[b,c,2i-1+y,2j-1+x] * Keff[o,c,p,q,y,x]
// Implicit GEMM: M=65536, N=384, K=1024, bf16 MFMA. Round 8:
//  - P_DW=168 (2P=16 mod 32): x-tile reads intra-phase conflict-free (r7 bug: P=165
//    aliased l4 groups 0/1 within lanes 0-31 -> 7.4M conflict cycles).
//  - Keff chunk (128n x 64k, 16KB) staged to LDS via global_load_lds, double-buffered,
//    XOR-swizzled (src unit u^(n&7); read unit (kk*4+l4)^(l15&7)) -> broadcast-free
//    8-lane phases; removes per-kk global A-loads AND the afc/afn regs (occupancy).
//  - One barrier per chunk; steady vmcnt(6); last chunk peeled with vmcnt(0).

#define IHW 128
#define CIN 64
#define COUT 96
#define NCK 16
#define P_DW 168
#define COFF_DW 80
#define XBUF_DW (12 * P_DW)  // 2016 dw
#define ABUF_DW 4096         // 128 rows x 32 dw

typedef __attribute__((ext_vector_type(8))) short short8_t;
typedef __attribute__((ext_vector_type(4))) float floatx4;

__device__ __forceinline__ short bf16r(float f) {
  uint32_t u = __float_as_uint(f);
  uint32_t r = (u + 0x7FFFu + ((u >> 16) & 1u)) >> 16;
  return (short)r;
}

__device__ __forceinline__ uint32_t pk(float lo, float hi) {
  union { __hip_bfloat16 h; unsigned short s; } a, bq;
  a.h = __float2bfloat16(lo);
  bq.h = __float2bfloat16(hi);
  return (uint32_t)a.s | ((uint32_t)bq.s << 16);
}

// ---------------- Keff precompute ----------------
__global__ void keff_kernel(const float* __restrict__ w, short* __restrict__ keff) {
  int idx = blockIdx.x * 256 + threadIdx.x;
  if (idx >= COUT * CIN) return;
  int o = idx / CIN, c = idx % CIN;
  int g = o / 32;

  int perm[4] = {0, 1, 2, 3};
  if (g == 1) { perm[0] = 1; perm[1] = 0; }
  else if (g == 2) { perm[0] = 3; perm[3] = 0; }

  const float H[4][4] = {{1,1,1,1},{1,-1,1,-1},{1,1,-1,-1},{1,-1,-1,1}};
  float S[2][4];
#pragma unroll
  for (int p = 0; p < 2; ++p)
#pragma unroll
    for (int a = 0; a < 4; ++a) {
      bool pos = (g == 1) ? ((p == 0) ? true : (a < 2))
                          : ((p == 0) ? ((a & 1) == 0) : (a < 2));
      S[p][a] = pos ? 1.f : -1.f;
    }

  float wv[4][4];
#pragma unroll
  for (int a = 0; a < 4; ++a)
#pragma unroll
    for (int d = 0; d < 4; ++d) wv[a][d] = w[(o * CIN + c) * 16 + a * 4 + d];

  for (int p = 0; p < 2; ++p)
    for (int q = 0; q < 2; ++q) {
      int n = o * 4 + p * 2 + q;
      for (int y = 0; y < 4; ++y)
        for (int xx = 0; xx < 4; ++xx) {
          float s = 0.f;
#pragma unroll
          for (int a = 0; a < 4; ++a) {
            float ea = S[p][a] * H[a][perm[xx]];
#pragma unroll
            for (int d = 0; d < 4; ++d) s += ea * S[q][d] * H[d][perm[y]] * wv[a][d];
          }
          keff[n * 1024 + c * 16 + y * 4 + xx] = bf16r(s);
        }
    }
}

// ---------------- main conv kernel ----------------
// block: 256 threads = 4 waves (2 M x 2 N). Tile M=128 patches, N=128. grid 1536.
__global__ __launch_bounds__(256) void conv_mfma(const float* __restrict__ x,
                                                 const short* __restrict__ keff,
                                                 const float* __restrict__ bias,
                                                 float* __restrict__ out) {
  __shared__ uint32_t xlds[2 * XBUF_DW];  // 16,128 B
  __shared__ uint32_t alds[2 * ABUF_DW];  // 32,768 B

  const int tid = threadIdx.x;
  const int lane = tid & 63;
  const int wid = tid >> 6;
  const int wavem = wid >> 1;
  const int wn = wid & 1;
  const int l15 = lane & 15;
  const int l4 = lane >> 4;

  // XCD-aware: 3 n-blocks of a tile + 64 consecutive tiles per XCD.
  const int hw = blockIdx.x;          // 0..1535
  const int xcd = hw & 7;
  const int r = hw >> 3;              // 0..191
  const int tile = xcd * 64 + r / 3;  // 0..511
  const int nblk = r % 3;             // 0..2
  const int b = tile >> 5;
  const int ib = tile & 31;
  const int gy0 = ib * 4 - 1;

  const float* xb = x + (size_t)b * CIN * IHW * IHW;

  // ---- x staging slots (3/thread): seg = c_sub*12 + rr, rr = kk2*6 + y ----
  int sl_off[3], sl_dw[3], sl_s[3];
  bool sl_ok[3];
#pragma unroll
  for (int it = 0; it < 3; ++it) {
    const int slot = tid + it * 256;
    const int seg = slot >> 5;
    const int s = slot & 31;
    const int c_sub = seg / 12;
    const int rr = seg % 12;
    const int kk2 = rr / 6;
    const int y = rr % 6;
    const int c_loc = 2 * kk2 + c_sub;
    const int gy = gy0 + y;
    const bool ok = (unsigned)gy < (unsigned)IHW;
    sl_off[it] = (c_loc * IHW + (ok ? gy : 0)) * IHW + 4 * s;
    sl_dw[it] = rr * P_DW + c_sub * COFF_DW;
    sl_s[it] = s;
    sl_ok[it] = ok;
  }

  // ---- A (keff) DMA slots (4/thread): slot = n*8 + u; src unit swizzled u^(n&7) ----
  int aoff[4];
#pragma unroll
  for (int it = 0; it < 4; ++it) {
    const int slot = tid + it * 256;
    const int n = slot >> 3;
    const int u = slot & 7;
    aoff[it] = (nblk * 128 + n) * 1024 + ((u ^ (n & 7)) << 3);
  }

  float4 gv[3];
  float gn[3];
#define ISSUE(ckv)                                                        \
  {                                                                       \
    _Pragma("unroll") for (int it = 0; it < 3; ++it) {                    \
      const float* p = xb + sl_off[it] + (size_t)(ckv) * (4 * IHW * IHW); \
      gv[it] = *reinterpret_cast<const float4*>(p);                       \
      gn[it] = (sl_s[it] < 31) ? p[4] : 0.f;                              \
    }                                                                     \
  }

#define WRITEST(bs)                                                       \
  {                                                                       \
    uint32_t* Bp = xlds + (bs) * XBUF_DW;                                 \
    _Pragma("unroll") for (int it = 0; it < 3; ++it) {                    \
      float4 v = gv[it];                                                  \
      float nx = gn[it];                                                  \
      if (!sl_ok[it]) { v.x = 0.f; v.y = 0.f; v.z = 0.f; v.w = 0.f; nx = 0.f; } \
      const int o = sl_dw[it] + 2 * sl_s[it] + 1;                         \
      Bp[o] = pk(v.y, v.z);                                               \
      Bp[o + 1] = pk(v.w, nx);                                            \
      if (sl_s[it] == 0) Bp[sl_dw[it]] = pk(0.f, v.x);                    \
    }                                                                     \
  }

#define ADMA(bs, ckv)                                                     \
  {                                                                       \
    _Pragma("unroll") for (int it = 0; it < 4; ++it) {                    \
      const short* src = keff + aoff[it] + (ckv) * 64;                    \
      __builtin_amdgcn_global_load_lds(                                   \
          (const __attribute__((address_space(1))) void*)src,             \
          (__attribute__((address_space(3))) void*)                       \
              &alds[(bs) * ABUF_DW + (tid + it * 256) * 4],               \
          16, 0, 0);                                                      \
    }                                                                     \
  }

#define COMPUTE(ckv)                                                      \
  {                                                                       \
    const uint32_t* Xp = xlds + ((ckv) & 1) * XBUF_DW;                    \
    const uint32_t* Ap = alds + ((ckv) & 1) * ABUF_DW;                    \
    _Pragma("unroll") for (int kk = 0; kk < 2; ++kk) {                    \
      short8_t af[4];                                                     \
      _Pragma("unroll") for (int nf = 0; nf < 4; ++nf) {                  \
        const int row = wn * 64 + nf * 16 + l15;                          \
        const int off = row * 32 + ((((kk << 2) | l4) ^ (l15 & 7)) << 2); \
        af[nf] = *reinterpret_cast<const short8_t*>(Ap + off);            \
      }                                                                   \
      const int od = cm_dw + kk * (6 * P_DW);                             \
      _Pragma("unroll") for (int mf = 0; mf < 4; ++mf) {                  \
        const int o = od + mf * 16;                                       \
        union { short8_t s8; uint32_t u[4]; } frag;                       \
        frag.u[0] = Xp[o];                                                \
        frag.u[1] = Xp[o + 1];                                            \
        frag.u[2] = Xp[o + P_DW];                                         \
        frag.u[3] = Xp[o + P_DW + 1];                                     \
        _Pragma("unroll") for (int nf = 0; nf < 4; ++nf)                  \
          acc[mf][nf] = __builtin_amdgcn_mfma_f32_16x16x32_bf16(          \
              af[nf], frag.s8, acc[mf][nf], 0, 0, 0);                     \
      }                                                                   \
    }                                                                     \
  }

  floatx4 acc[4][4];
#pragma unroll
  for (int i = 0; i < 4; ++i)
#pragma unroll
    for (int j2 = 0; j2 < 4; ++j2) acc[i][j2] = (floatx4){0.f, 0.f, 0.f, 0.f};

  float biasr[4];
#pragma unroll
  for (int nf = 0; nf < 4; ++nf) biasr[nf] = bias[nblk * 32 + wn * 16 + nf * 4 + l4];

  // per-lane x-tile read base (dwords)
  const int cm_dw = (2 * wavem + 2 * (l4 & 1)) * P_DW + (l4 >> 1) * COFF_DW + l15;

  // ---- prologue: stage chunk 0 (A-DMA + x), issue chunk 1 ----
  ISSUE(0);
  ADMA(0, 0);
  __builtin_amdgcn_sched_barrier(0);
  WRITEST(0);  // auto-waits gv(0)
  ISSUE(1);

  // ---- main loop: chunks 0..14 (each stages ck+1, computes ck) ----
  for (int ck = 0; ck < NCK - 1; ++ck) {
    asm volatile("s_waitcnt vmcnt(6) lgkmcnt(0)" ::: "memory");
    __builtin_amdgcn_s_barrier();
    __builtin_amdgcn_sched_barrier(0);

    const int nb = (ck + 1) & 1;
    ADMA(nb, ck + 1);
    __builtin_amdgcn_sched_barrier(0);
    WRITEST(nb);                       // gv(ck+1), auto vmcnt
    if (ck + 2 < NCK) ISSUE(ck + 2);
    COMPUTE(ck);
  }

  // ---- peeled last chunk (vmcnt(0): only A-DMA(15) outstanding) ----
  asm volatile("s_waitcnt vmcnt(0) lgkmcnt(0)" ::: "memory");
  __builtin_amdgcn_s_barrier();
  __builtin_amdgcn_sched_barrier(0);
  COMPUTE(NCK - 1);

  // ---- epilogue (validated r2 mapping) ----
  const int i_row = ib * 2 + wavem;
  const int orow0 = 2 * i_row;
#pragma unroll
  for (int nf = 0; nf < 4; ++nf) {
    const int o = nblk * 32 + wn * 16 + nf * 4 + l4;
    const float bv = biasr[nf];
    float* obase = out + ((size_t)(b * COUT + o) * IHW + orow0) * IHW;
#pragma unroll
    for (int mf = 0; mf < 4; ++mf) {
      const int col = 2 * (mf * 16 + l15);
      float2 s0 = make_float2(acc[mf][nf][0] + bv, acc[mf][nf][1] + bv);
      float2 s1 = make_float2(acc[mf][nf][2] + bv, acc[mf][nf][3] + bv);
      *reinterpret_cast<float2*>(obase + col) = s0;
      *reinterpret_cast<float2*>(obase + IHW + col) = s1;
    }
  }
#undef ISSUE
#undef WRITEST
#undef ADMA
#undef COMPUTE
}

extern "C" void kernel_launch(void* const* d_in, const int* in_sizes, int n_in,
                              void* d_out, int out_size, void* d_ws, size_t ws_size,
                              hipStream_t stream) {
  const float* x = (const float*)d_in[0];
  const float* w = (const float*)d_in[1];
  const float* bias = (const float*)d_in[2];
  float* out = (float*)d_out;
  short* keff = (short*)d_ws;  // 786432 B

  hipLaunchKernelGGL(keff_kernel, dim3(24), dim3(256), 0, stream, w, keff);
  hipLaunchKernelGGL(conv_mfma, dim3(1536), dim3(256), 0, stream, x, keff, bias, out);
}